// Round 7
// baseline (202.240 us; speedup 1.0000x reference)
//
#include <hip/hip_runtime.h>

#define R_    512
#define K_    17
#define HIN   56
#define WIN   56
#define OUTS  96
#define NMAP  (R_ * K_)
#define NT    384      // 6 waves/block
#define GRID  1088     // persistent: each block pipelines ITERS map-pairs
#define ITERS 4        // 1088*4 = 4352 = NMAP/2
#define RST   98       // tmp row stride in v2f units (784 B)
#define TROWS 60       // phys rows: 0,1 = pad(row0); 2..57 = rows 0..55; 58,59 = pad(row55)
#define RAWST 58       // raw row stride (dwords): even -> b64-aligned; 58%32 pattern <=4-way
#define RAWMAP (HIN * RAWST)   // 3248 dwords per map

typedef float v2f __attribute__((ext_vector_type(2)));

constexpr float cubic_c(float xin) {
    float x = xin < 0.0f ? -xin : xin;
    const float A = -0.75f;
    if (x <= 1.0f) return ((A + 2.0f) * x - (A + 3.0f)) * x * x + 1.0f;
    if (x < 2.0f)  return A * (((x - 5.0f) * x + 8.0f) * x - 4.0f);
    return 0.0f;
}

// X-pass: folded effective weights on contiguous window [s, s+3] (border clamp folded).
struct XTabT {
    float w[OUTS][4];
    int   s[OUTS];
    constexpr XTabT() : w{}, s{} {
        for (int o = 0; o < OUTS; ++o) {
            float src = ((float)o + 0.5f) * (56.0f / 96.0f) - 0.5f;
            int base = (int)src;
            if ((float)base > src) --base;
            int st = base - 1;
            if (st < 0) st = 0;
            if (st > HIN - 4) st = HIN - 4;
            s[o] = st;
            for (int q = 0; q < 4; ++q) {
                int tap = base - 1 + q;
                float wt = cubic_c(src - (float)tap);
                int p = tap < 0 ? 0 : (tap > HIN - 1 ? HIN - 1 : tap);
                w[o][p - st] += wt;
            }
        }
    }
};
constexpr XTabT XT;

// Y-pass: period-12 raw weights + relative tap start d (logical tap0 row = 7*(h/12)+d[h%12]).
// Border handled by replicated pad rows in tmp (validated: prior sessions absmax 0.0).
struct YTabT {
    float w[12][4];
    int   d[12];
    constexpr YTabT() : w{}, d{} {
        for (int ph = 0; ph < 12; ++ph) {
            float src = ((float)ph + 0.5f) * (56.0f / 96.0f) - 0.5f;
            int base = (int)src;
            if ((float)base > src) --base;
            d[ph] = base - 1;
            for (int q = 0; q < 4; ++q)
                w[ph][q] = cubic_c(src - (float)(base - 1 + q));
        }
    }
};
constexpr YTabT YT;

// 16-col strips, uniform 4-float4 windows (verified vs XT.s ranges, absmax 0.0 in R6):
//   G0 s[0,7]:FS=0  G1 s[8,16]:FS=1  G2 s[17,26]:FS=4
//   G3 s[26,35]:FS=6  G4 s[36,44]:FS=8  G5 s[45,52]:FS=10   (win = floats [4FS, 4FS+15])
template<int G> struct FSv {
    static constexpr int v = (G == 0) ? 0 : (G == 1) ? 1 : (G == 2) ? 4
                           : (G == 3) ? 6 : (G == 4) ? 8 : 10;
};

// ---- y-value for (col, hh within quarter q): c[] base = phys row 14q;
// relative tap0 = 7*(hh/12) + d[hh%12] + 2 in [0,14]; +3 taps -> c[18].
__device__ __forceinline__ v2f yv(const v2f* c, int hh) {
    const int ph = hh % 12, bb = hh / 12;
    const int i0 = 7 * bb + YT.d[ph] + 2;           // compile-time after unroll
    v2f acc = c[i0] * (v2f){YT.w[ph][0], YT.w[ph][0]};
    acc = __builtin_elementwise_fma((v2f){YT.w[ph][1], YT.w[ph][1]}, c[i0 + 1], acc);
    acc = __builtin_elementwise_fma((v2f){YT.w[ph][2], YT.w[ph][2]}, c[i0 + 2], acc);
    acc = __builtin_elementwise_fma((v2f){YT.w[ph][3], YT.w[ph][3]}, c[i0 + 3], acc);
    return acc;
}

// ---- phase 1 for one lane: read 16-float window of both maps from raw LDS,
// zip, folded-weight X-FMA (bit-identical chain to R0/R1), write tmp. ----
template<int G>
__device__ __forceinline__ void p1_lds(const float* rA, const float* rB, v2f* dst) {
    constexpr int FS = FSv<G>::v;
    v2f rr[16];
#pragma unroll
    for (int k = 0; k < 8; ++k) {                   // all static indices
        v2f a = *(const v2f*)(rA + 4 * FS + 2 * k); // ds_read_b64 (RAWST even -> aligned)
        v2f b = *(const v2f*)(rB + 4 * FS + 2 * k);
        rr[2 * k]     = (v2f){a.x, b.x};
        rr[2 * k + 1] = (v2f){a.y, b.y};
    }
#pragma unroll
    for (int i = 0; i < 8; ++i) {
        const int o0 = 16 * G + 2 * i, o1 = o0 + 1;
        const int s0 = XT.s[o0] - 4 * FS, s1 = XT.s[o1] - 4 * FS;  // compile-time, [0,12]
        v2f x0 = rr[s0] * (v2f){XT.w[o0][0], XT.w[o0][0]};
        x0 = __builtin_elementwise_fma((v2f){XT.w[o0][1], XT.w[o0][1]}, rr[s0 + 1], x0);
        x0 = __builtin_elementwise_fma((v2f){XT.w[o0][2], XT.w[o0][2]}, rr[s0 + 2], x0);
        x0 = __builtin_elementwise_fma((v2f){XT.w[o0][3], XT.w[o0][3]}, rr[s0 + 3], x0);
        v2f x1 = rr[s1] * (v2f){XT.w[o1][0], XT.w[o1][0]};
        x1 = __builtin_elementwise_fma((v2f){XT.w[o1][1], XT.w[o1][1]}, rr[s1 + 1], x1);
        x1 = __builtin_elementwise_fma((v2f){XT.w[o1][2], XT.w[o1][2]}, rr[s1 + 2], x1);
        x1 = __builtin_elementwise_fma((v2f){XT.w[o1][3], XT.w[o1][3]}, rr[s1 + 3], x1);
        float4 st = {x0.x, x0.y, x1.x, x1.y};
        *(float4*)(dst + 2 * i) = st;               // ds_write_b128, 16B-aligned
    }
}

__global__ __launch_bounds__(NT, 3)
void _Keypointer_kernel(const float* __restrict__ masks,
                        const float* __restrict__ boxes,
                        float* __restrict__ out) {
    __shared__ float raw[2 * RAWMAP];               // 25,984 B: padded raw input, 1 buffer
    __shared__ __align__(16) v2f tmp[TROWS * RST];  // 47,040 B
    __shared__ v2f wvmax[6];
    __shared__ int wppos[6][2];

    const int t = threadIdx.x;
    const int g = t >> 6;                           // wave id / col group (wave-uniform)
    const int w = t & 63;

    // ---- fixed per-thread stage mapping: float4 #f -> padded raw dword offset ----
    // f = t + 384*i (i<4); tail f = 1536+t for t<32. Computed ONCE (loop-invariant).
    int off0, off1, off2, off3, off4;
#define MKOFF(f_, dst_) { const int f = (f_); const int mp = (f >= 784);          \
        const int rem = f - 784 * mp; const int row = rem / 14;                   \
        const int c4 = rem - 14 * row; dst_ = mp * RAWMAP + row * RAWST + 4 * c4; }
    MKOFF(t,        off0) MKOFF(t + 384,  off1)
    MKOFF(t + 768,  off2) MKOFF(t + 1152, off3)
    MKOFF(1536 + (t & 31), off4)                    // meaningful only for t < 32
#undef MKOFF

    // phase-1 geometry (lane = row; pads replicated)
    const int srcrow = min(max(w - 2, 0), HIN - 1);
    const int phys   = min(w, TROWS - 1);
    v2f* dst = tmp + phys * RST + 16 * g;
    const float* rA = raw + srcrow * RAWST;         // map0 row window base
    const float* rB = rA + RAWMAP;                  // map1

    // phase-2 geometry (thread = (col, row-quarter))
    const int q   = t / 96;
    const int col = t - 96 * q;
    const int h0  = 24 * q;
    const v2f* crd = tmp + (14 * q) * RST + col;

    float4 V0, V1, V2, V3, V4;                      // named prefetch regs (R3 lesson)

    int pair = blockIdx.x;

#define LOADP(p_) { const float4* gs = (const float4*)(masks + (size_t)(2 * (p_)) * (HIN * WIN)); \
        V0 = gs[t]; V1 = gs[t + 384]; V2 = gs[t + 768]; V3 = gs[t + 1152];                        \
        if (t < 32) V4 = gs[1536 + t]; }
#define STAGE() { *(v2f*)(raw + off0) = (v2f){V0.x, V0.y}; *(v2f*)(raw + off0 + 2) = (v2f){V0.z, V0.w}; \
        *(v2f*)(raw + off1) = (v2f){V1.x, V1.y}; *(v2f*)(raw + off1 + 2) = (v2f){V1.z, V1.w};           \
        *(v2f*)(raw + off2) = (v2f){V2.x, V2.y}; *(v2f*)(raw + off2 + 2) = (v2f){V2.z, V2.w};           \
        *(v2f*)(raw + off3) = (v2f){V3.x, V3.y}; *(v2f*)(raw + off3 + 2) = (v2f){V3.z, V3.w};           \
        if (t < 32) { *(v2f*)(raw + off4) = (v2f){V4.x, V4.y}; *(v2f*)(raw + off4 + 2) = (v2f){V4.z, V4.w}; } }

    // prologue: stage pair 0 (cold latency paid once per block, amortized over ITERS)
    LOADP(pair)
    STAGE()
    __syncthreads();

    for (int it = 0; it < ITERS; ++it) {
        const int bm0 = 2 * pair;
        const bool more = (it + 1 < ITERS);

        // prefetch next pair: contiguous float4, 1KB/wave-instruction, in flight
        // across phase 1 + barrier (consumed at STAGE after BAR1)
        if (more) LOADP(pair + GRID)

        // ---- phase 1: raw LDS -> x-resized tmp (bit-identical chain) ----
        if      (g == 0) p1_lds<0>(rA, rB, dst);
        else if (g == 1) p1_lds<1>(rA, rB, dst);
        else if (g == 2) p1_lds<2>(rA, rB, dst);
        else if (g == 3) p1_lds<3>(rA, rB, dst);
        else if (g == 4) p1_lds<4>(rA, rB, dst);
        else             p1_lds<5>(rA, rB, dst);
        __syncthreads();                            // BAR1: tmp ready; raw fully consumed

        // stage next pair into raw now — ds_writes overlap phase-2 compute
        if (more) STAGE()

        // ---- phase 2: y-resize + in-register lexicographic argmax (R6-validated) ----
        v2f c[18];
#pragma unroll
        for (int i = 0; i < 18; ++i) c[i] = crd[i * RST];   // ds_read_b64, imm offsets

        v2f sv = {-INFINITY, -INFINITY};
        int h0i = 0, h1i = 0;
#pragma unroll
        for (int hh = 0; hh < 24; ++hh) {
            v2f a = yv(c, hh);
            if (a.x > sv.x) { sv.x = a.x; h0i = hh; }  // strict >: min-fp within thread
            if (a.y > sv.y) { sv.y = a.y; h1i = hh; }
        }
        float m0 = sv.x, m1 = sv.y;
        int p0 = (h0 + h0i) * OUTS + col;
        int p1 = (h0 + h1i) * OUTS + col;

        // wave reduce: max value, min flat-pos on ties (== jnp.argmax first-occurrence)
#pragma unroll
        for (int off = 32; off; off >>= 1) {
            float t0 = __shfl_xor(m0, off, 64); int u0 = __shfl_xor(p0, off, 64);
            if (t0 > m0 || (t0 == m0 && u0 < p0)) { m0 = t0; p0 = u0; }
            float t1 = __shfl_xor(m1, off, 64); int u1 = __shfl_xor(p1, off, 64);
            if (t1 > m1 || (t1 == m1 && u1 < p1)) { m1 = t1; p1 = u1; }
        }
        if (w == 0) { wvmax[g] = (v2f){m0, m1}; wppos[g][0] = p0; wppos[g][1] = p1; }
        __syncthreads();                            // BAR2: wmax ready; stage-writes done;
                                                    // tmp reads done before next overwrite
        if (t < 2) {
            float M = -INFINITY; int P = 0x7fffffff;
#pragma unroll
            for (int j = 0; j < 6; ++j) {           // lexicographic combine: commutative
                const float v = t ? wvmax[j].y : wvmax[j].x;
                const int  pp = wppos[j][t];
                if (v > M || (v == M && pp < P)) { M = v; P = pp; }
            }
            const int map = bm0 + t;
            const int r = map / K_, k = map - r * K_;
            const int y = P / OUTS, x = P - y * OUTS;
            const float b0f = boxes[r * 4 + 0], b1f = boxes[r * 4 + 1];
            const float b2f = boxes[r * 4 + 2], b3f = boxes[r * 4 + 3];
            const float corr0 = fmaxf(b2f - b0f, 1.0f) / (float)OUTS;
            const float corr1 = fmaxf(b3f - b1f, 1.0f) / (float)OUTS;
            out[(r * 3 + 0) * K_ + k] = ((float)y + 0.5f) * corr0 + b0f;
            out[(r * 3 + 1) * K_ + k] = ((float)x + 0.5f) * corr1 + b1f;
            out[(r * 3 + 2) * K_ + k] = 1.0f;
            out[R_ * 3 * K_ + r * K_ + k] = M;
        }
        pair += GRID;
    }
#undef LOADP
#undef STAGE
}

extern "C" void kernel_launch(void* const* d_in, const int* in_sizes, int n_in,
                              void* d_out, int out_size, void* d_ws, size_t ws_size,
                              hipStream_t stream) {
    const float* masks = (const float*)d_in[0];
    const float* boxes = (const float*)d_in[1];
    float* out = (float*)d_out;
    _Keypointer_kernel<<<GRID, NT, 0, stream>>>(masks, boxes, out);
}

// Round 8
// 185.737 us; speedup vs baseline: 1.0889x; 1.0889x over previous
//
#include <hip/hip_runtime.h>

#define R_    512
#define K_    17
#define HIN   56
#define WIN   56
#define OUTS  96
#define NMAP  (R_ * K_)
#define NT    64      // ONE wave per block: no __syncthreads anywhere
#define GRID  (NMAP / 2)
#define WST   18      // strip row stride in v2f units (144 B)
#define TROWS 60      // phys rows: 0,1 = pad(row0); 2..57 = rows 0..55; 58,59 = pad(row55)
#define RAWST 58      // raw row stride (dwords): even -> b64-aligned; ~4-way conflicts max
#define RAWMAP (HIN * RAWST)   // 3248 dwords per map

typedef float v2f __attribute__((ext_vector_type(2)));

// LDS fence: pin scheduling on both sides of the waitcnt (guide rule #18; validated R6).
#define LDS_FENCE() do {                                      \
        __builtin_amdgcn_sched_barrier(0);                    \
        asm volatile("s_waitcnt lgkmcnt(0)" ::: "memory");    \
        __builtin_amdgcn_sched_barrier(0);                    \
    } while (0)

constexpr float cubic_c(float xin) {
    float x = xin < 0.0f ? -xin : xin;
    const float A = -0.75f;
    if (x <= 1.0f) return ((A + 2.0f) * x - (A + 3.0f)) * x * x + 1.0f;
    if (x < 2.0f)  return A * (((x - 5.0f) * x + 8.0f) * x - 4.0f);
    return 0.0f;
}

// X-pass: folded effective weights on contiguous window [s, s+3] (border clamp folded).
struct XTabT {
    float w[OUTS][4];
    int   s[OUTS];
    constexpr XTabT() : w{}, s{} {
        for (int o = 0; o < OUTS; ++o) {
            float src = ((float)o + 0.5f) * (56.0f / 96.0f) - 0.5f;
            int base = (int)src;
            if ((float)base > src) --base;
            int st = base - 1;
            if (st < 0) st = 0;
            if (st > HIN - 4) st = HIN - 4;
            s[o] = st;
            for (int q = 0; q < 4; ++q) {
                int tap = base - 1 + q;
                float wt = cubic_c(src - (float)tap);
                int p = tap < 0 ? 0 : (tap > HIN - 1 ? HIN - 1 : tap);
                w[o][p - st] += wt;
            }
        }
    }
};
constexpr XTabT XT;

// Y-pass: period-12 raw weights + relative tap start d (logical tap0 row = 7*(h/12)+d[h%12]).
// Border handled by replicated pad rows in tmp (validated: prior sessions absmax 0.0).
struct YTabT {
    float w[12][4];
    int   d[12];
    constexpr YTabT() : w{}, d{} {
        for (int ph = 0; ph < 12; ++ph) {
            float src = ((float)ph + 0.5f) * (56.0f / 96.0f) - 0.5f;
            int base = (int)src;
            if ((float)base > src) --base;
            d[ph] = base - 1;
            for (int q = 0; q < 4; ++q)
                w[ph][q] = cubic_c(src - (float)(base - 1 + q));
        }
    }
};
constexpr YTabT YT;

// 16-col strips, windows = raw floats [4FS, 4FS+15] (verified vs XT.s ranges; R6 absmax 0.0):
//   G0 s[0,7]:FS=0  G1 s[8,16]:FS=1  G2 s[17,26]:FS=4
//   G3 s[26,35]:FS=6  G4 s[36,44]:FS=8  G5 s[45,52]:FS=10
template<int G> struct FSv {
    static constexpr int v = (G == 0) ? 0 : (G == 1) ? 1 : (G == 2) ? 4
                           : (G == 3) ? 6 : (G == 4) ? 8 : 10;
};

// ---- y-value for (col, hh within quarter q): c[] base = phys row 14q;
// relative tap0 = 7*(hh/12) + d[hh%12] + 2 in [0,14]; +3 taps -> c[18].
__device__ __forceinline__ v2f yv(const v2f* c, int hh) {
    const int ph = hh % 12, bb = hh / 12;
    const int i0 = 7 * bb + YT.d[ph] + 2;           // compile-time after unroll
    v2f acc = c[i0] * (v2f){YT.w[ph][0], YT.w[ph][0]};
    acc = __builtin_elementwise_fma((v2f){YT.w[ph][1], YT.w[ph][1]}, c[i0 + 1], acc);
    acc = __builtin_elementwise_fma((v2f){YT.w[ph][2], YT.w[ph][2]}, c[i0 + 2], acc);
    acc = __builtin_elementwise_fma((v2f){YT.w[ph][3], YT.w[ph][3]}, c[i0 + 3], acc);
    return acc;
}

// ---- one 16-col strip, entirely wave-internal (R6-validated structure; source of the
// window is now the raw LDS stage — same float values -> bit-identical results).
// NOTE: pointers alias the same LDS by design — NO __restrict__ (R4 lesson).
template<int G>
__device__ __forceinline__ void strip_comp(const float* rA,  // raw + srcrow*RAWST
                                           const float* rB,  // rA + RAWMAP
                                           v2f* wrow,        // tmp + phys*WST
                                           const v2f* crd,   // tmp + 14q*WST + cc
                                           int pbase,        // 24q*96 + cc
                                           float& m0, int& p0, float& m1, int& p1) {
    constexpr int FS = FSv<G>::v;

    // WAR fence: previous strip's tmp reads retired before we overwrite tmp.
    LDS_FENCE();

    v2f rr[16];
#pragma unroll
    for (int k = 0; k < 8; ++k) {                   // ds_read_b64 (even dword -> aligned)
        v2f a = *(const v2f*)(rA + 4 * FS + 2 * k);
        v2f b = *(const v2f*)(rB + 4 * FS + 2 * k);
        rr[2 * k]     = (v2f){a.x, b.x};
        rr[2 * k + 1] = (v2f){a.y, b.y};
    }
#pragma unroll
    for (int i = 0; i < 8; ++i) {
        const int o0 = 16 * G + 2 * i, o1 = o0 + 1;
        const int s0 = XT.s[o0] - 4 * FS, s1 = XT.s[o1] - 4 * FS;  // compile-time, [0,12]
        v2f x0 = rr[s0] * (v2f){XT.w[o0][0], XT.w[o0][0]};
        x0 = __builtin_elementwise_fma((v2f){XT.w[o0][1], XT.w[o0][1]}, rr[s0 + 1], x0);
        x0 = __builtin_elementwise_fma((v2f){XT.w[o0][2], XT.w[o0][2]}, rr[s0 + 2], x0);
        x0 = __builtin_elementwise_fma((v2f){XT.w[o0][3], XT.w[o0][3]}, rr[s0 + 3], x0);
        v2f x1 = rr[s1] * (v2f){XT.w[o1][0], XT.w[o1][0]};
        x1 = __builtin_elementwise_fma((v2f){XT.w[o1][1], XT.w[o1][1]}, rr[s1 + 1], x1);
        x1 = __builtin_elementwise_fma((v2f){XT.w[o1][2], XT.w[o1][2]}, rr[s1 + 2], x1);
        x1 = __builtin_elementwise_fma((v2f){XT.w[o1][3], XT.w[o1][3]}, rr[s1 + 3], x1);
        float4 st = {x0.x, x0.y, x1.x, x1.y};
        *(float4*)(wrow + 2 * i) = st;              // ds_write_b128, 16B-aligned
    }
    // RAW fence: wave-wide ds_writes drained before cross-lane tmp reads.
    LDS_FENCE();

    v2f c[18];
#pragma unroll
    for (int i = 0; i < 18; ++i) c[i] = crd[i * WST];  // ds_read_b64, imm offsets

    v2f sv = {-INFINITY, -INFINITY};
    int h0i = 0, h1i = 0;
#pragma unroll
    for (int hh = 0; hh < 24; ++hh) {
        v2f a = yv(c, hh);
        if (a.x > sv.x) { sv.x = a.x; h0i = hh; }   // strict > : first (min-fp) within strip
        if (a.y > sv.y) { sv.y = a.y; h1i = hh; }
    }
    const int fp0 = pbase + 16 * G + h0i * 96;
    const int fp1 = pbase + 16 * G + h1i * 96;
    if (sv.x > m0 || (sv.x == m0 && fp0 < p0)) { m0 = sv.x; p0 = fp0; }
    if (sv.y > m1 || (sv.y == m1 && fp1 < p1)) { m1 = sv.y; p1 = fp1; }
}

__global__ __launch_bounds__(NT)
void _Keypointer_kernel(const float* __restrict__ masks,
                        const float* __restrict__ boxes,
                        float* __restrict__ out) {
    __shared__ float raw[2 * RAWMAP];               // 25,984 B — contiguously staged pair
    __shared__ __align__(16) v2f tmp[TROWS * WST];  //  8,640 B — strip buffer
                                                    // total 34.6 KB -> 4 blocks/CU

    const int w   = threadIdx.x;                    // 0..63, one wave
    const int bm0 = 2 * blockIdx.x;

    // ---- stage: contiguous global (1KB/wave-instruction, fill-like) -> padded raw ----
    // 1568 float4 per pair; lane w takes f = w + 64j (j<24) plus tail f = 1536+w (w<32).
    {
        const float4* gs = (const float4*)(masks + (size_t)bm0 * (HIN * WIN));
        float4 v[25];                               // fully-unrolled static idx -> VGPRs
        int ofs[25];
#pragma unroll
        for (int j = 0; j < 25; ++j) {
            const int f = w + 64 * j;
            if (j < 24 || w < 32) {
                v[j] = gs[f];
                const int mp  = (f >= 784) ? 1 : 0;
                const int rem = f - 784 * mp;
                const int row = rem / 14;
                const int c4  = rem - 14 * row;
                ofs[j] = mp * RAWMAP + row * RAWST + 4 * c4;   // even -> b64-aligned
            }
        }
#pragma unroll
        for (int j = 0; j < 25; ++j) {
            if (j < 24 || w < 32) {
                *(v2f*)(raw + ofs[j])     = (v2f){v[j].x, v[j].y};
                *(v2f*)(raw + ofs[j] + 2) = (v2f){v[j].z, v[j].w};
            }
        }
    }
    LDS_FENCE();                                    // stage visible before strip reads

    // phase-1 role: lane = phys row (pads replicated; lanes 60..63 dup phys 59)
    const int srcrow = min(max(w - 2, 0), HIN - 1);
    const int phys   = min(w, TROWS - 1);
    const float* rA = raw + srcrow * RAWST;
    const float* rB = rA + RAWMAP;
    v2f* wrow = tmp + phys * WST;

    // phase-2 role: lane = (col-in-strip, row-quarter); 16x4 = 64, bijective
    const int cc = w & 15, q = w >> 4;
    const v2f* crd = tmp + (14 * q) * WST + cc;
    const int pbase = (24 * q) * OUTS + cc;

    float m0 = -INFINITY, m1 = -INFINITY;
    int   p0 = 0x7fffffff, p1 = 0x7fffffff;

    strip_comp<0>(rA, rB, wrow, crd, pbase, m0, p0, m1, p1);
    strip_comp<1>(rA, rB, wrow, crd, pbase, m0, p0, m1, p1);
    strip_comp<2>(rA, rB, wrow, crd, pbase, m0, p0, m1, p1);
    strip_comp<3>(rA, rB, wrow, crd, pbase, m0, p0, m1, p1);
    strip_comp<4>(rA, rB, wrow, crd, pbase, m0, p0, m1, p1);
    strip_comp<5>(rA, rB, wrow, crd, pbase, m0, p0, m1, p1);

    // wave argmax reduce: max value, min flat-pos on ties (== jnp.argmax first-occurrence)
#pragma unroll
    for (int off = 32; off; off >>= 1) {
        float t0 = __shfl_xor(m0, off, 64); int u0 = __shfl_xor(p0, off, 64);
        if (t0 > m0 || (t0 == m0 && u0 < p0)) { m0 = t0; p0 = u0; }
        float t1 = __shfl_xor(m1, off, 64); int u1 = __shfl_xor(p1, off, 64);
        if (t1 > m1 || (t1 == m1 && u1 < p1)) { m1 = t1; p1 = u1; }
    }

    if (w == 0) {
#pragma unroll
        for (int mi = 0; mi < 2; ++mi) {
            const int map = bm0 + mi;
            const float M = mi ? m1 : m0;
            const int bp  = mi ? p1 : p0;
            const int r = map / K_, k = map - r * K_;
            const int y = bp / OUTS, x = bp - y * OUTS;
            const float b0f = boxes[r * 4 + 0], b1f = boxes[r * 4 + 1];
            const float b2f = boxes[r * 4 + 2], b3f = boxes[r * 4 + 3];
            const float corr0 = fmaxf(b2f - b0f, 1.0f) / (float)OUTS;
            const float corr1 = fmaxf(b3f - b1f, 1.0f) / (float)OUTS;
            out[(r * 3 + 0) * K_ + k] = ((float)y + 0.5f) * corr0 + b0f;
            out[(r * 3 + 1) * K_ + k] = ((float)x + 0.5f) * corr1 + b1f;
            out[(r * 3 + 2) * K_ + k] = 1.0f;
            out[R_ * 3 * K_ + r * K_ + k] = M;
        }
    }
}

extern "C" void kernel_launch(void* const* d_in, const int* in_sizes, int n_in,
                              void* d_out, int out_size, void* d_ws, size_t ws_size,
                              hipStream_t stream) {
    const float* masks = (const float*)d_in[0];
    const float* boxes = (const float*)d_in[1];
    float* out = (float*)d_out;
    _Keypointer_kernel<<<GRID, NT, 0, stream>>>(masks, boxes, out);
}